// Round 6
// baseline (203.009 us; speedup 1.0000x reference)
//
#include <hip/hip_runtime.h>
#include <cstdint>
#include <cstddef>

#define NUM_LAYERS 20
#define HID 1024
#define M_TOTAL 8192

typedef __attribute__((ext_vector_type(8))) short bf16x8;
typedef __attribute__((ext_vector_type(4))) float f32x4;
typedef __attribute__((ext_vector_type(8))) unsigned short u16x8;

typedef __attribute__((address_space(1))) unsigned int as1_u32;
typedef __attribute__((address_space(3))) unsigned int as3_u32;

__device__ __forceinline__ unsigned short f2bf(float f) {
  union { float f; unsigned int u; } v; v.f = f;
  unsigned int r = v.u + 0x7fffu + ((v.u >> 16) & 1u);  // RNE
  return (unsigned short)(r >> 16);
}

__device__ __forceinline__ u16x8 pack8(f32x4 a, f32x4 b) {
  u16x8 o;
  o[0] = f2bf(a[0]); o[1] = f2bf(a[1]); o[2] = f2bf(a[2]); o[3] = f2bf(a[3]);
  o[4] = f2bf(b[0]); o[5] = f2bf(b[1]); o[6] = f2bf(b[2]); o[7] = f2bf(b[3]);
  return o;
}

// async global->LDS, 16B/lane; LDS ptr must be wave-uniform base (HW adds lane*16)
__device__ __forceinline__ void load16_lds(const void* g, void* l) {
  __builtin_amdgcn_global_load_lds(
      reinterpret_cast<as1_u32*>(reinterpret_cast<uintptr_t>(g)),
      reinterpret_cast<as3_u32*>(reinterpret_cast<uintptr_t>(l)),
      16, 0, 0);
}

// ---- Kernel 1: conv_w 20-layer sum -> bf16 wb ([N][K] = B^T). 40 float4 loads
// in flight per thread (R4 fix: 36-VGPR version was MLP-bound at 1.2 TB/s).
__global__ __launch_bounds__(256, 1) void wsum_kernel(const float* __restrict__ w,
                                                      unsigned short* __restrict__ wb) {
  const int P = blockIdx.x * 256 + threadIdx.x;  // ushort8 index; float4 pair (2P,2P+1)
  const f32x4* p = reinterpret_cast<const f32x4*>(w);
  f32x4 va[NUM_LAYERS], vb[NUM_LAYERS];
#pragma unroll
  for (int l = 0; l < NUM_LAYERS; ++l) {
    const f32x4* pl = p + (size_t)l * (HID * HID / 4) + (size_t)2 * P;
    va[l] = __builtin_nontemporal_load(pl);
    vb[l] = __builtin_nontemporal_load(pl + 1);
  }
  f32x4 s0 = va[0], s1 = vb[0];
#pragma unroll
  for (int l = 1; l < NUM_LAYERS; ++l) { s0 += va[l]; s1 += vb[l]; }
  reinterpret_cast<u16x8*>(wb)[P] = pack8(s0, s1);
}

// ---- Kernel 2: fused GEMM + RMSNorm. ----
// Grid 256 x 512 threads. Block: rows [bid*32, bid*32+32) x ALL 1024 cols, so the
// RMS reduction is block-local. Reads x fp32 directly (xb eliminated); acc stays
// fp32 into the norm (cb eliminated). B (2 MiB bf16) re-streams from L2/L3 per
// block via global_load_lds. A-tile staged regs->ds_write with stride-40 padding
// (2-way banks = free, rows 80 B = 16B-aligned for ds_read_b128).
// out = C * 32 * rsqrt(sum C^2 + 400*eps*H) * norm_w   (/20 folded into scale)
__global__ __launch_bounds__(512, 1) void fused_kernel(const float* __restrict__ x,
                                                       const unsigned short* __restrict__ wb,
                                                       const float* __restrict__ nw,
                                                       float* __restrict__ out) {
  __shared__ unsigned short lB[1024 * 32];  // 64 KiB, [n][32] (global_load_lds: no pad)
  __shared__ unsigned short lA[32 * 40];    // 2.5 KiB, padded stride 40
  __shared__ float rowss[32];

  const int tid = threadIdx.x;
  const int lane = tid & 63;
  const int wv = tid >> 6;     // 0..7, covers cols [wv*128, wv*128+128)
  const int quad = lane >> 4;  // 0..3
  const int c16 = lane & 15;

  const int m0 = blockIdx.x * 32;

  // B staging: per issue (128 n-rows): thread t -> n = t>>2, koff = (t&3)*8
  const unsigned short* gB = wb + (size_t)(tid >> 2) * HID + (tid & 3) * 8;

  // A staging: threads 0..255: am = t>>3 (0..31), ak = (t&7)*4
  const int am = tid >> 3;
  const int ak = (tid & 7) * 4;
  const float* gA = x + (size_t)(m0 + am) * HID + ak;

  f32x4 acc[2][8] = {};

  for (int k0 = 0; k0 < HID; k0 += 32) {
    __syncthreads();  // prior iter's ds_reads done before overwrite
    if (tid < 256) {
      f32x4 v = *reinterpret_cast<const f32x4*>(gA);
      ushort4 o;
      o.x = f2bf(v[0]); o.y = f2bf(v[1]); o.z = f2bf(v[2]); o.w = f2bf(v[3]);
      *reinterpret_cast<ushort4*>(lA + am * 40 + ak) = o;
    }
    gA += 32;
#pragma unroll
    for (int s = 0; s < 8; ++s)
      load16_lds(gB + (size_t)(s * 128) * HID, lB + s * 4096 + wv * 512);
    gB += 32;
    __syncthreads();  // staging visible (vmcnt+lgkmcnt drained by compiler)

    bf16x8 af[2], bf[8];
#pragma unroll
    for (int i = 0; i < 2; ++i)
      af[i] = *reinterpret_cast<const bf16x8*>(lA + (i * 16 + c16) * 40 + quad * 8);
#pragma unroll
    for (int j = 0; j < 8; ++j)
      bf[j] = *reinterpret_cast<const bf16x8*>(lB + (wv * 128 + j * 16 + c16) * 32 + quad * 8);
#pragma unroll
    for (int i = 0; i < 2; ++i)
#pragma unroll
      for (int j = 0; j < 8; ++j)
        acc[i][j] = __builtin_amdgcn_mfma_f32_16x16x32_bf16(af[i], bf[j], acc[i][j], 0, 0, 0);
  }

  // ---- fused RMS norm epilogue ----
  if (tid < 32) rowss[tid] = 0.f;
  __syncthreads();

  // C/D layout: row = quad*4 + r (within 16-tile), col = c16.
  // 16 lanes (same quad, c16=0..15) hold different cols of the same row.
#pragma unroll
  for (int i = 0; i < 2; ++i) {
#pragma unroll
    for (int r = 0; r < 4; ++r) {
      float ssp = 0.f;
#pragma unroll
      for (int j = 0; j < 8; ++j) ssp += acc[i][j][r] * acc[i][j][r];
      ssp += __shfl_xor(ssp, 1, 64);
      ssp += __shfl_xor(ssp, 2, 64);
      ssp += __shfl_xor(ssp, 4, 64);
      ssp += __shfl_xor(ssp, 8, 64);
      if (c16 == 0) atomicAdd(&rowss[i * 16 + quad * 4 + r], ssp);
    }
  }
  __syncthreads();

  float nwv[8];
#pragma unroll
  for (int j = 0; j < 8; ++j) nwv[j] = nw[wv * 128 + j * 16 + c16];

#pragma unroll
  for (int i = 0; i < 2; ++i) {
#pragma unroll
    for (int r = 0; r < 4; ++r) {
      const int row = i * 16 + quad * 4 + r;
      const float sc = 32.0f * rsqrtf(rowss[row] + 0.4096f);  // 32=sqrt(H); 0.4096=eps*H*400
      float* orow = out + (size_t)(m0 + row) * HID + wv * 128 + c16;
#pragma unroll
      for (int j = 0; j < 8; ++j)
        orow[j * 16] = acc[i][j][r] * sc * nwv[j];
    }
  }
}

extern "C" void kernel_launch(void* const* d_in, const int* in_sizes, int n_in,
                              void* d_out, int out_size, void* d_ws, size_t ws_size,
                              hipStream_t stream) {
  const float* x = (const float*)d_in[0];       // [2,4096,1024] fp32
  const float* conv_w = (const float*)d_in[1];  // [20,1024,1024] fp32
  const float* norm_w = (const float*)d_in[2];  // [1024] fp32
  float* out = (float*)d_out;                   // [2,4096,1024] fp32

  unsigned short* wb = (unsigned short*)d_ws;   // 2 MiB: summed W bf16 ([N][K])

  wsum_kernel<<<512, 256, 0, stream>>>(conv_w, wb);
  fused_kernel<<<M_TOTAL / 32, 512, 0, stream>>>(x, wb, norm_w, out);
}